// Round 7
// baseline (681.726 us; speedup 1.0000x reference)
//
#include <hip/hip_runtime.h>
#include <hip/hip_cooperative_groups.h>

namespace cg = cooperative_groups;

#define N_PTS 131072
#define C_DIM 128
#define NS_K  16
#define BN_EPS 1e-5f
#define GRID_BLOCKS 512

typedef unsigned short ushort_t;
typedef unsigned short u16x8 __attribute__((ext_vector_type(8)));
typedef __bf16 bf16x8 __attribute__((ext_vector_type(8)));
typedef float f32x4 __attribute__((ext_vector_type(4)));

__device__ __forceinline__ ushort_t f2b(float f) {
    unsigned int u = __float_as_uint(f);
    u += 0x7FFFu + ((u >> 16) & 1u);          // round-to-nearest-even
    return (ushort_t)(u >> 16);
}
__device__ __forceinline__ float b2f(ushort_t h) {
    return __uint_as_float((unsigned int)h << 16);
}

// ===========================================================================
// Cooperative mega-kernel path. LDS budget 53,248 B (<64 KB): a_sh 64x136,
// w_sh 128x136, s_red 256 floats. GEMM = 4 sub-tiles of 64 rows per block.
// Fragment layouts (proven rounds 2-5): A[m=lane&15][k=q*8+j];
// B[k=q*8+j][n=lane&15] from wT[n][k]; C/D col=lane&15, row=q*4+reg.
// ===========================================================================
template <bool A_BF16, bool STATS>
__device__ __forceinline__ void gemm_phase(
    const void* __restrict__ Aptr, const ushort_t* __restrict__ wT,
    const float* __restrict__ bias, ushort_t* __restrict__ outp,
    ushort_t* a_sh, ushort_t* w_sh, float* s_red,
    float* __restrict__ gsum, float* __restrict__ gsq,
    const int bid, const int tid)
{
    const int lane = tid & 63;
    const int wv   = tid >> 6;
    const int m16  = lane & 15;
    const int q    = lane >> 4;

    // ---- stage wT -> w_sh once (vector copy, pitch 136) ----
    {
        const int n    = tid >> 1;
        const int half = (tid & 1) * 64;
        const ushort_t* wg = wT + (size_t)n * 128 + half;
        ushort_t* wsp = w_sh + n * 136 + half;
        #pragma unroll
        for (int j = 0; j < 8; j++)
            *(u16x8*)(wsp + j * 8) = *(const u16x8*)(wg + j * 8);
    }
    if (STATS) s_red[tid] = 0.f;   // sum[0:128), sq[128:256)

    float psum[8], psq[8];
    #pragma unroll
    for (int c = 0; c < 8; c++) { psum[c] = 0.f; psq[c] = 0.f; }

    for (int st = 0; st < 4; st++) {
        const int base = (bid * 4 + st) * 64;
        __syncthreads();   // st=0: W staged; st>0: prev C-store LDS reads done

        // ---- stage A sub-tile (64 rows x 128 k) ----
        {
            const int row = tid >> 2;          // 0..63
            const int qtr = (tid & 3) * 32;
            ushort_t* as = a_sh + row * 136 + qtr;
            if (A_BF16) {
                const ushort_t* ag = (const ushort_t*)Aptr + (size_t)(base + row) * 128 + qtr;
                #pragma unroll
                for (int j = 0; j < 4; j++)
                    *(u16x8*)(as + j * 8) = *(const u16x8*)(ag + j * 8);
            } else {
                const float* ag = (const float*)Aptr + (size_t)(base + row) * 128 + qtr;
                #pragma unroll
                for (int j = 0; j < 4; j++) {
                    f32x4 lo = *(const f32x4*)(ag + j * 8);
                    f32x4 hi = *(const f32x4*)(ag + j * 8 + 4);
                    u16x8 v;
                    v[0] = f2b(lo[0]); v[1] = f2b(lo[1]); v[2] = f2b(lo[2]); v[3] = f2b(lo[3]);
                    v[4] = f2b(hi[0]); v[5] = f2b(hi[1]); v[6] = f2b(hi[2]); v[7] = f2b(hi[3]);
                    *(u16x8*)(as + j * 8) = v;
                }
            }
        }
        __syncthreads();

        f32x4 acc[8];
        #pragma unroll
        for (int c = 0; c < 8; c++) acc[c] = (f32x4){0.f, 0.f, 0.f, 0.f};

        const ushort_t* ap = a_sh + (wv * 16 + m16) * 136 + q * 8;
        const ushort_t* wp = w_sh + m16 * 136 + q * 8;

        #pragma unroll
        for (int k0 = 0; k0 < 128; k0 += 32) {
            bf16x8 a = __builtin_bit_cast(bf16x8, *(const u16x8*)(ap + k0));
            #pragma unroll
            for (int c = 0; c < 8; c++) {
                bf16x8 b = __builtin_bit_cast(bf16x8, *(const u16x8*)(wp + c * (16 * 136) + k0));
                acc[c] = __builtin_amdgcn_mfma_f32_16x16x32_bf16(a, b, acc[c], 0, 0, 0);
            }
        }
        __syncthreads();   // MFMA LDS reads done; a_sh reusable as C tile

        // ---- epilogue: bias, bf16 -> LDS C tile, BN partial sums ----
        #pragma unroll
        for (int c = 0; c < 8; c++) {
            const int col = c * 16 + m16;
            const float bv = bias[col];
            const int rb = wv * 16 + q * 4;
            #pragma unroll
            for (int r = 0; r < 4; r++) {
                const float v = acc[c][r] + bv;
                a_sh[(rb + r) * 136 + col] = f2b(v);
                if (STATS) { psum[c] += v; psq[c] += v * v; }
            }
        }
        __syncthreads();

        // ---- coalesced write-out: 16 lanes cover one 256 B row ----
        {
            const int r0 = tid >> 4;
            const int c0 = (tid & 15) * 8;
            #pragma unroll
            for (int it = 0; it < 4; it++) {
                const int rl = r0 + it * 16;
                const u16x8 v = *(const u16x8*)(a_sh + rl * 136 + c0);
                *(u16x8*)(outp + (size_t)(base + rl) * 128 + c0) = v;
            }
        }
    }

    if (STATS) {
        #pragma unroll
        for (int c = 0; c < 8; c++) {
            atomicAdd(&s_red[c * 16 + m16], psum[c]);
            atomicAdd(&s_red[128 + c * 16 + m16], psq[c]);
        }
        __syncthreads();
        if (tid < 128) {
            atomicAdd(&gsum[tid], s_red[tid]);
            atomicAdd(&gsq[tid],  s_red[128 + tid]);
        }
    }
}

__global__ __launch_bounds__(256) void mega_kernel(
    const float* __restrict__ p, const float* __restrict__ u,
    const int* __restrict__ o, const int* __restrict__ idx,
    const float* __restrict__ W1, const float* __restrict__ b1,
    const float* __restrict__ W2, const float* __restrict__ b2,
    const float* __restrict__ gamma, const float* __restrict__ beta,
    float* __restrict__ out, ushort_t* __restrict__ table,
    ushort_t* __restrict__ lap, ushort_t* __restrict__ h,
    float* __restrict__ gsum, float* __restrict__ gsq,
    ushort_t* __restrict__ wT1, ushort_t* __restrict__ wT2)
{
    cg::grid_group grid = cg::this_grid();

    __shared__ __align__(16) ushort_t a_sh[64 * 136];    // 17408 B
    __shared__ __align__(16) ushort_t w_sh[128 * 136];   // 34816 B
    __shared__ float s_red[256];                         //  1024 B

    const int bid = blockIdx.x;
    const int tid = threadIdx.x;
    const int t   = bid * 256 + tid;        // 0..131071

    // ========== phase 0: prep wT, zero stats, copy p, write o ==========
    if (t < 16384) {
        const int n = t & 127;
        const int k = t >> 7;
        wT1[n * 128 + k] = f2b(W1[k * 128 + n]);
        wT2[n * 128 + k] = f2b(W2[k * 128 + n]);
    }
    if (t < 128) gsum[t] = 0.f;
    else if (t < 256) gsq[t - 128] = 0.f;
    if (t < 3 * N_PTS / 4)
        *(f32x4*)(out + (size_t)t * 4) = *(const f32x4*)(p + (size_t)t * 4);
    if (t == 0)
        out[(size_t)3 * N_PTS + (size_t)N_PTS * C_DIM] = (float)o[0];

    __threadfence();
    grid.sync();

    // ========== phase 1: table = bf16(u @ W1 + b1) ==========
    gemm_phase<false, false>(u, wT1, b1, table, a_sh, w_sh, s_red,
                             nullptr, nullptr, bid, tid);
    __threadfence();
    grid.sync();

    // ========== phase 2: lap = mean_s relu(table[idx] - table) ==========
    {
        int* s_idx = (int*)a_sh;
        const int pp = tid >> 4;
        const int c8 = (tid & 15) * 8;
        for (int it = 0; it < 16; it++) {
            const int ib = bid * 16 + it;
            __syncthreads();
            s_idx[tid] = idx[(size_t)ib * 256 + tid];
            __syncthreads();

            const size_t pt = (size_t)ib * 16 + pp;
            const u16x8 cv = *(const u16x8*)(table + pt * 128 + c8);
            float ctr[8], acc[8];
            #pragma unroll
            for (int e = 0; e < 8; e++) { ctr[e] = b2f(cv[e]); acc[e] = 0.f; }

            #pragma unroll
            for (int s = 0; s < NS_K; s++) {
                const int j = s_idx[pp * 16 + s];
                const u16x8 nv = *(const u16x8*)(table + (size_t)j * 128 + c8);
                #pragma unroll
                for (int e = 0; e < 8; e++)
                    acc[e] += fmaxf(b2f(nv[e]) - ctr[e], 0.f);
            }
            u16x8 ov;
            #pragma unroll
            for (int e = 0; e < 8; e++) ov[e] = f2b(acc[e] * (1.f / (float)NS_K));
            *(u16x8*)(lap + pt * 128 + c8) = ov;
        }
    }
    __threadfence();
    grid.sync();

    // ========== phase 3: h = bf16(lap @ W2 + b2), BN sums ==========
    gemm_phase<true, true>(lap, wT2, b2, h, a_sh, w_sh, s_red,
                           gsum, gsq, bid, tid);
    __threadfence();
    grid.sync();

    // ========== phase 4: out = relu(BN(h)) ==========
    {
        float* s_sc  = (float*)a_sh;       // [128]
        float* s_sh2 = s_sc + 128;         // [128]
        __syncthreads();
        if (tid < 128) {
            const float invN = 1.f / (float)N_PTS;
            const float mean = gsum[tid] * invN;
            const float var  = gsq[tid] * invN - mean * mean;
            const float sc   = rsqrtf(var + BN_EPS) * gamma[tid];
            s_sc[tid]  = sc;
            s_sh2[tid] = fmaf(-mean, sc, beta[tid]);
        }
        __syncthreads();

        const int c8 = (tid * 8) & 127;
        for (int it = 0; it < 16; it++) {
            const size_t i = ((size_t)bid * 16 + it) * 256 + tid;   // bf16x8 idx
            const u16x8 hv = *(const u16x8*)(h + i * 8);
            f32x4 o0, o1;
            #pragma unroll
            for (int e = 0; e < 4; e++) {
                o0[e] = fmaxf(fmaf(b2f(hv[e]),     s_sc[c8 + e],     s_sh2[c8 + e]),     0.f);
                o1[e] = fmaxf(fmaf(b2f(hv[4 + e]), s_sc[c8 + 4 + e], s_sh2[c8 + 4 + e]), 0.f);
            }
            float* op = out + (size_t)3 * N_PTS + i * 8;
            *(f32x4*)(op)     = o0;
            *(f32x4*)(op + 4) = o1;
        }
    }
}

// ===========================================================================
// Fallback path: exact round-4 kernels (proven 288 us / absmax 0.046875).
// ===========================================================================
__global__ __launch_bounds__(256) void prep_w_kernel(
    const float* __restrict__ W1, const float* __restrict__ W2,
    ushort_t* __restrict__ wT1, ushort_t* __restrict__ wT2)
{
    const int t = blockIdx.x * 256 + threadIdx.x;
    const int n = t & 127;
    const int k = t >> 7;
    wT1[n * 128 + k] = f2b(W1[k * 128 + n]);
    wT2[n * 128 + k] = f2b(W2[k * 128 + n]);
}

template <bool A_BF16, bool STATS>
__global__ __launch_bounds__(256) void gemm_mfma_kernel(
    const void* __restrict__ Aptr, const ushort_t* __restrict__ wT,
    const float* __restrict__ bias, ushort_t* __restrict__ out,
    float* __restrict__ gsum, float* __restrict__ gsq)
{
    __shared__ __align__(16) ushort_t a_sh[128 * 136];
    __shared__ __align__(16) ushort_t w_sh[128 * 136];
    __shared__ float s_sum[128];
    __shared__ float s_sq[128];

    const int tid  = threadIdx.x;
    const int lane = tid & 63;
    const int wv   = tid >> 6;
    const int m16  = lane & 15;
    const int q    = lane >> 4;
    const int base = blockIdx.x * 128;

    if (STATS && tid < 128) { s_sum[tid] = 0.f; s_sq[tid] = 0.f; }

    {
        const int row  = tid >> 1;
        const int half = (tid & 1) * 64;
        ushort_t* as = a_sh + row * 136 + half;
        if (A_BF16) {
            const ushort_t* ag = (const ushort_t*)Aptr + (size_t)(base + row) * 128 + half;
            #pragma unroll
            for (int j = 0; j < 8; j++)
                *(u16x8*)(as + j * 8) = *(const u16x8*)(ag + j * 8);
        } else {
            const float* ag = (const float*)Aptr + (size_t)(base + row) * 128 + half;
            #pragma unroll
            for (int j = 0; j < 8; j++) {
                f32x4 lo = *(const f32x4*)(ag + j * 8);
                f32x4 hi = *(const f32x4*)(ag + j * 8 + 4);
                u16x8 v;
                v[0] = f2b(lo[0]); v[1] = f2b(lo[1]); v[2] = f2b(lo[2]); v[3] = f2b(lo[3]);
                v[4] = f2b(hi[0]); v[5] = f2b(hi[1]); v[6] = f2b(hi[2]); v[7] = f2b(hi[3]);
                *(u16x8*)(as + j * 8) = v;
            }
        }
    }
    {
        const int n    = tid >> 1;
        const int half = (tid & 1) * 64;
        const ushort_t* wg = wT + (size_t)n * 128 + half;
        ushort_t* ws = w_sh + n * 136 + half;
        #pragma unroll
        for (int j = 0; j < 8; j++)
            *(u16x8*)(ws + j * 8) = *(const u16x8*)(wg + j * 8);
    }
    __syncthreads();

    f32x4 acc[2][8];
    #pragma unroll
    for (int i = 0; i < 2; i++)
        #pragma unroll
        for (int c = 0; c < 8; c++) acc[i][c] = (f32x4){0.f, 0.f, 0.f, 0.f};

    const ushort_t* ap0 = a_sh + ((wv * 2 + 0) * 16 + m16) * 136 + q * 8;
    const ushort_t* ap1 = a_sh + ((wv * 2 + 1) * 16 + m16) * 136 + q * 8;
    const ushort_t* wp  = w_sh + m16 * 136 + q * 8;

    #pragma unroll
    for (int k0 = 0; k0 < 128; k0 += 32) {
        bf16x8 a0 = __builtin_bit_cast(bf16x8, *(const u16x8*)(ap0 + k0));
        bf16x8 a1 = __builtin_bit_cast(bf16x8, *(const u16x8*)(ap1 + k0));
        #pragma unroll
        for (int c = 0; c < 8; c++) {
            bf16x8 b = __builtin_bit_cast(bf16x8, *(const u16x8*)(wp + c * (16 * 136) + k0));
            acc[0][c] = __builtin_amdgcn_mfma_f32_16x16x32_bf16(a0, b, acc[0][c], 0, 0, 0);
            acc[1][c] = __builtin_amdgcn_mfma_f32_16x16x32_bf16(a1, b, acc[1][c], 0, 0, 0);
        }
    }

    __syncthreads();

    float psum[8], psq[8];
    #pragma unroll
    for (int c = 0; c < 8; c++) { psum[c] = 0.f; psq[c] = 0.f; }

    #pragma unroll
    for (int c = 0; c < 8; c++) {
        const int col = c * 16 + m16;
        const float bv = bias[col];
        #pragma unroll
        for (int i = 0; i < 2; i++) {
            const int rb = (wv * 2 + i) * 16 + q * 4;
            #pragma unroll
            for (int r = 0; r < 4; r++) {
                const float v = acc[i][c][r] + bv;
                a_sh[(rb + r) * 136 + col] = f2b(v);
                if (STATS) { psum[c] += v; psq[c] += v * v; }
            }
        }
    }
    if (STATS) {
        #pragma unroll
        for (int c = 0; c < 8; c++) {
            atomicAdd(&s_sum[c * 16 + m16], psum[c]);
            atomicAdd(&s_sq[c * 16 + m16],  psq[c]);
        }
    }
    __syncthreads();

    {
        const int r0 = tid >> 4;
        const int c0 = (tid & 15) * 8;
        #pragma unroll
        for (int it = 0; it < 8; it++) {
            const int rl = r0 + it * 16;
            const u16x8 v = *(const u16x8*)(a_sh + rl * 136 + c0);
            *(u16x8*)(out + (size_t)(base + rl) * 128 + c0) = v;
        }
    }
    if (STATS && tid < 128) {
        atomicAdd(&gsum[tid], s_sum[tid]);
        atomicAdd(&gsq[tid],  s_sq[tid]);
    }
}

__global__ __launch_bounds__(256) void laplacian_kernel(
    const ushort_t* __restrict__ table, const int* __restrict__ idx,
    ushort_t* __restrict__ lap)
{
    __shared__ int s_idx[256];
    const int tid = threadIdx.x;
    s_idx[tid] = idx[blockIdx.x * 256 + tid];
    __syncthreads();

    const int p  = tid >> 4;
    const int c8 = (tid & 15) * 8;
    const size_t pt = (size_t)blockIdx.x * 16 + p;

    const u16x8 cv = *(const u16x8*)(table + pt * 128 + c8);
    float ctr[8];
    #pragma unroll
    for (int e = 0; e < 8; e++) ctr[e] = b2f(cv[e]);

    float acc[8];
    #pragma unroll
    for (int e = 0; e < 8; e++) acc[e] = 0.f;

    #pragma unroll
    for (int s = 0; s < NS_K; s++) {
        const int j = s_idx[p * 16 + s];
        const u16x8 nv = *(const u16x8*)(table + (size_t)j * 128 + c8);
        #pragma unroll
        for (int e = 0; e < 8; e++)
            acc[e] += fmaxf(b2f(nv[e]) - ctr[e], 0.f);
    }

    u16x8 o;
    #pragma unroll
    for (int e = 0; e < 8; e++) o[e] = f2b(acc[e] * (1.f / (float)NS_K));
    *(u16x8*)(lap + pt * 128 + c8) = o;
}

__global__ void bn_stats_kernel(const float* __restrict__ gsum,
                                const float* __restrict__ gsq,
                                const float* __restrict__ gamma,
                                const float* __restrict__ beta,
                                float* __restrict__ bnsc, float* __restrict__ bnsh)
{
    const int c = threadIdx.x;
    const float invN = 1.f / (float)N_PTS;
    const float mean = gsum[c] * invN;
    const float var  = gsq[c] * invN - mean * mean;
    const float sc   = rsqrtf(var + BN_EPS) * gamma[c];
    bnsc[c] = sc;
    bnsh[c] = fmaf(-mean, sc, beta[c]);
}

__global__ __launch_bounds__(256) void bn_relu_kernel(
    const ushort_t* __restrict__ h, const float* __restrict__ bnsc,
    const float* __restrict__ bnsh, float* __restrict__ out)
{
    const size_t i = (size_t)blockIdx.x * 256 + threadIdx.x;
    const int c8 = (threadIdx.x * 8) & 127;

    const u16x8 hv = *(const u16x8*)(h + i * 8);
    const f32x4 sc0 = *(const f32x4*)(bnsc + c8);
    const f32x4 sc1 = *(const f32x4*)(bnsc + c8 + 4);
    const f32x4 sh0 = *(const f32x4*)(bnsh + c8);
    const f32x4 sh1 = *(const f32x4*)(bnsh + c8 + 4);

    f32x4 o0, o1;
    #pragma unroll
    for (int e = 0; e < 4; e++) {
        o0[e] = fmaxf(fmaf(b2f(hv[e]),     sc0[e], sh0[e]), 0.f);
        o1[e] = fmaxf(fmaf(b2f(hv[4 + e]), sc1[e], sh1[e]), 0.f);
    }
    float* op = out + (size_t)3 * N_PTS + i * 8;
    *(f32x4*)(op)     = o0;
    *(f32x4*)(op + 4) = o1;
}

__global__ __launch_bounds__(256) void copy_p_kernel(
    const float* __restrict__ p, const int* __restrict__ o,
    float* __restrict__ out)
{
    const size_t i = (size_t)blockIdx.x * 256 + threadIdx.x;
    *(f32x4*)(out + i * 4) = *(const f32x4*)(p + i * 4);
    if (i == 0)
        out[(size_t)3 * N_PTS + (size_t)N_PTS * C_DIM] = (float)o[0];
}

extern "C" void kernel_launch(void* const* d_in, const int* in_sizes, int n_in,
                              void* d_out, int out_size, void* d_ws, size_t ws_size,
                              hipStream_t stream) {
    const float* p     = (const float*)d_in[0];
    const float* u     = (const float*)d_in[1];
    const int*   o     = (const int*)d_in[2];
    const int*   idx   = (const int*)d_in[3];
    const float* W1    = (const float*)d_in[4];
    const float* b1    = (const float*)d_in[5];
    const float* W2    = (const float*)d_in[6];
    const float* b2    = (const float*)d_in[7];
    const float* gamma = (const float*)d_in[8];
    const float* beta  = (const float*)d_in[9];
    float* out = (float*)d_out;

    char* ws = (char*)d_ws;
    const size_t buf_bytes = (size_t)N_PTS * C_DIM * sizeof(ushort_t);  // 32 MB
    ushort_t* table = (ushort_t*)ws;
    ushort_t* lap   = (ushort_t*)(ws + buf_bytes);
    ushort_t* h     = (ushort_t*)(ws + 2 * buf_bytes);
    float*    stats = (float*)(ws + 3 * buf_bytes);
    float* gsum = stats;        // [128]
    float* gsq  = stats + 128;  // [128]
    float* bnsc = stats + 256;  // [128]
    float* bnsh = stats + 384;  // [128]
    ushort_t* wT1 = (ushort_t*)(stats + 512);              // [128*128] bf16
    ushort_t* wT2 = wT1 + 128 * 128;

    void* kargs[] = { (void*)&p, (void*)&u, (void*)&o, (void*)&idx,
                      (void*)&W1, (void*)&b1, (void*)&W2, (void*)&b2,
                      (void*)&gamma, (void*)&beta, (void*)&out,
                      (void*)&table, (void*)&lap, (void*)&h,
                      (void*)&gsum, (void*)&gsq, (void*)&wT1, (void*)&wT2 };

    hipError_t err = hipLaunchCooperativeKernel(
        (const void*)mega_kernel, dim3(GRID_BLOCKS), dim3(256), kargs, 0, stream);

    if (err != hipSuccess) {
        // Fallback: proven round-4 multi-kernel sequence.
        (void)hipGetLastError();
        hipMemsetAsync(stats, 0, 256 * sizeof(float), stream);
        prep_w_kernel<<<64, 256, 0, stream>>>(W1, W2, wT1, wT2);
        gemm_mfma_kernel<false, false><<<N_PTS / 128, 256, 0, stream>>>(
            u, wT1, b1, table, nullptr, nullptr);
        laplacian_kernel<<<N_PTS / 16, 256, 0, stream>>>(table, idx, lap);
        gemm_mfma_kernel<true, true><<<N_PTS / 128, 256, 0, stream>>>(
            lap, wT2, b2, h, gsum, gsq);
        bn_stats_kernel<<<1, 128, 0, stream>>>(gsum, gsq, gamma, beta, bnsc, bnsh);
        bn_relu_kernel<<<(N_PTS * C_DIM / 8) / 256, 256, 0, stream>>>(
            h, bnsc, bnsh, out);
        copy_p_kernel<<<(3 * N_PTS / 4) / 256, 256, 0, stream>>>(p, o, out);
    }
}